// Round 17
// baseline (307.983 us; speedup 1.0000x reference)
//
#include <hip/hip_runtime.h>

typedef __attribute__((ext_vector_type(8))) short short8;    // bf16x8 MFMA frag
typedef __attribute__((ext_vector_type(8))) unsigned short ushort8;
typedef __attribute__((ext_vector_type(4))) unsigned short ushort4v;
typedef __attribute__((ext_vector_type(4))) float f32x4;
typedef __attribute__((ext_vector_type(2))) unsigned int uint2v;
typedef unsigned short ushort;
typedef unsigned int uint;

#define QS2F (0.17677669529663687f * 1.4426950408889634f) // 1/sqrt(32) * log2(e)

__device__ __forceinline__ ushort f2bf(float f) {
  union { float f; unsigned u; } a; a.f = f;
  unsigned r = a.u + 0x7fffu + ((a.u >> 16) & 1u);
  return (ushort)(r >> 16);
}
__device__ __forceinline__ float bf2f(ushort u) {
  union { uint u; float f; } a; a.u = ((uint)u) << 16; return a.f;
}
__device__ __forceinline__ uint cvtpk(float a, float b) {  // low16=bf(a), high16=bf(b)
  uint r; asm("v_cvt_pk_bf16_f32 %0, %1, %2" : "=v"(r) : "v"(a), "v"(b)); return r;
}
__device__ __forceinline__ float ex2(float x) {  // raw v_exp_f32 (2^x), single instr
  return __builtin_amdgcn_exp2f(x);
}

__device__ __forceinline__ void gload16(const void* g, void* l) {
  __builtin_amdgcn_global_load_lds((const __attribute__((address_space(1))) void*)g,
                                   (__attribute__((address_space(3))) void*)l, 16, 0, 0);
}

// bijective XCD swizzle (m204): hwid -> logical wg, chunked per XCD
__device__ __forceinline__ uint xcd_swz(uint hwid, uint nwg) {
  const uint q8 = nwg >> 3, r8 = nwg & 7;
  const uint xcd = hwid & 7, i8 = hwid >> 3;
  return (xcd < r8 ? xcd * (q8 + 1) : r8 * (q8 + 1) + (xcd - r8) * q8) + i8;
}

// ---------------- segment starts (batch sorted & contiguous) ----------------
__global__ __launch_bounds__(256) void seg_start_k(const int* __restrict__ batch,
                                                   int* __restrict__ start) {
  const int i = blockIdx.x * 256 + threadIdx.x;
  const int b = batch[i];
  if (i == 0 || batch[i - 1] != b) start[b] = i;
  if (i == 0) start[256] = 65536;
}

// ---------------- weight transpose + bf16 convert (Wq pre-scaled for exp2) ----------------
__global__ __launch_bounds__(256) void prep_w_k(
    const float* __restrict__ Wq, const float* __restrict__ Wk,
    const float* __restrict__ Wv, const float* __restrict__ Wo,
    const float* __restrict__ W1, const float* __restrict__ W2,
    ushort* __restrict__ Wt) {
  const int w = blockIdx.y;
  const float* src; ushort* dst; int Kd, Nd; float sc = 1.0f;
  switch (w) {
    case 0: src = Wq; dst = Wt;          Kd = 256; Nd = 256; sc = QS2F; break;
    case 1: src = Wk; dst = Wt + 65536;  Kd = 256; Nd = 256; break;
    case 2: src = Wv; dst = Wt + 131072; Kd = 256; Nd = 256; break;
    case 3: src = Wo; dst = Wt + 196608; Kd = 256; Nd = 256; break;
    case 4: src = W1; dst = Wt + 262144; Kd = 256; Nd = 512; break;
    default: src = W2; dst = Wt + 393216; Kd = 512; Nd = 256; break;
  }
  const int e = blockIdx.x * 256 + threadIdx.x;
  if (e < Kd * Nd) {
    const int k = e / Nd, n = e - k * Nd;
    dst[n * Kd + k] = f2bf(src[e] * sc);
  }
}

// ---------------- pack x -> dense bf16 [G*257][256] ----------------
__global__ __launch_bounds__(256) void pack_xd_k(
    const float* __restrict__ x, const float* __restrict__ cls,
    const int* __restrict__ start, ushort* __restrict__ xd) {
  const size_t idx = (((size_t)blockIdx.x << 8) + threadIdx.x) << 3;  // 8 cols/thread
  const int row = (int)(idx >> 8);
  const int col = (int)(idx & 255);
  const int g = row / 257, n = row - g * 257;
  const int sg = start[g], cn = start[g + 1] - sg;
  float4 a, b;
  if (n < cn) {
    const float* src = x + (((size_t)(sg + n)) << 8) + col;
    a = ((const float4*)src)[0]; b = ((const float4*)src)[1];
  } else if (n == 256) {
    const float* src = cls + (((size_t)g) << 8) + col;
    a = ((const float4*)src)[0]; b = ((const float4*)src)[1];
  } else {
    a.x = a.y = a.z = a.w = 0.f; b = a;
  }
  ushort8 o;
  o[0] = f2bf(a.x); o[1] = f2bf(a.y); o[2] = f2bf(a.z); o[3] = f2bf(a.w);
  o[4] = f2bf(b.x); o[5] = f2bf(b.y); o[6] = f2bf(b.z); o[7] = f2bf(b.w);
  *(ushort8*)(xd + idx) = o;
}

// ============ GEMM variant A: 128x128 tile, 4 waves, 256 thr, single-buf 32KB ============
// EPI 0: +bias -> bf16 (by encodes (z, n-half) for fused QKV; Q bias scaled by QS2F)
// EPI 2: relu(+bias) -> bf16 (by = n-block of N)
// EPI 4: +bias + bf16 resid(dense m) -> bf16 SCATTERED to compact row r2
template<int EPI>
__device__ __forceinline__ void gemm_a_body(
    const ushort* __restrict__ A, const ushort* __restrict__ Bt,
    int N, int K,
    const float* __restrict__ b0, const float* __restrict__ b1, const float* __restrict__ b2,
    ushort* __restrict__ o0, ushort* __restrict__ o1, ushort* __restrict__ o2,
    const ushort* __restrict__ resid, const int* __restrict__ start) {
  __shared__ __align__(16) char As[16384];  // 128 x 128B, XOR-swizzled
  __shared__ __align__(16) char Bs[16384];
  const int tid = threadIdx.x, lane = tid & 63, wid = tid >> 6;
  const int hi = lane >> 4, lc = lane & 15;
  const int wm = wid >> 1, wn = wid & 1;

  const uint nx = gridDim.x, ny = gridDim.y;
  const uint hwid = blockIdx.y * nx + blockIdx.x;
  const uint wg = xcd_swz(hwid, nx * ny);
  const int bx = wg / ny, by = wg % ny;

  const int m0 = bx * 128;
  const int z = (EPI == 0) ? (by >> 1) : 0;
  const int ncol0 = (EPI == 0) ? (by & 1) * 128 : by * 128;
  const ushort* Bz = (EPI == 0) ? Bt + (size_t)z * 65536 : Bt;
  const float* bias = (EPI == 0) ? (z == 0 ? b0 : (z == 1 ? b1 : b2)) : b0;
  const float bmul = (EPI == 0 && z == 0) ? QS2F : 1.0f;
  ushort* obf = (EPI == 0) ? (z == 0 ? o0 : (z == 1 ? o1 : o2)) : o0;

  f32x4 acc[4][4];
#pragma unroll
  for (int a = 0; a < 4; ++a)
#pragma unroll
    for (int b = 0; b < 4; ++b) acc[a][b] = (f32x4)0.0f;

  for (int kt = 0; kt < K; kt += 64) {
#pragma unroll
    for (int r = 0; r < 4; ++r) {
      const int L = (r * 256 + tid) * 16;
      const int row = L >> 7;
      const int cb = (L & 127) ^ ((row & 7) << 4);
      gload16(A + (size_t)(m0 + row) * K + kt + (cb >> 1), As + L);
    }
#pragma unroll
    for (int r = 0; r < 4; ++r) {
      const int L = (r * 256 + tid) * 16;
      const int row = L >> 7;
      const int cb = (L & 127) ^ ((row & 7) << 4);
      gload16(Bz + (size_t)(ncol0 + row) * K + kt + (cb >> 1), Bs + L);
    }
    asm volatile("s_waitcnt vmcnt(0)" ::: "memory");
    __syncthreads();
#pragma unroll
    for (int ks = 0; ks < 2; ++ks) {
      short8 af[4], bfr[4];
      const int cB = (ks * 32 + hi * 8) * 2;
#pragma unroll
      for (int t = 0; t < 4; ++t) {
        const int rA = wm * 64 + t * 16 + lc;
        af[t] = *(const short8*)(As + (rA << 7) + (cB ^ ((rA & 7) << 4)));
        const int rB = wn * 64 + t * 16 + lc;
        bfr[t] = *(const short8*)(Bs + (rB << 7) + (cB ^ ((rB & 7) << 4)));
      }
#pragma unroll
      for (int mt = 0; mt < 4; ++mt)
#pragma unroll
        for (int nt = 0; nt < 4; ++nt)
          acc[mt][nt] = __builtin_amdgcn_mfma_f32_16x16x32_bf16(af[mt], bfr[nt], acc[mt][nt], 0, 0, 0);
    }
    __syncthreads();
  }

#pragma unroll
  for (int mt = 0; mt < 4; ++mt)
#pragma unroll
    for (int i = 0; i < 4; ++i) {
      const int m = m0 + wm * 64 + mt * 16 + hi * 4 + i;
      size_t r2 = (size_t)m;
      bool wr = true;
      if constexpr (EPI == 4) {
        // dense row m -> compact row r2 (nodes in x-order, then CLS block)
        const int gg = m / 257, nr = m - gg * 257;
        const int sg = start[gg], cn = start[gg + 1] - sg;
        if (nr < cn) r2 = (size_t)(sg + nr);
        else if (nr == 256) r2 = (size_t)(65536 + gg);
        else wr = false;
      }
#pragma unroll
      for (int nt = 0; nt < 4; ++nt) {
        const int n = ncol0 + wn * 64 + nt * 16 + lc;
        if constexpr (EPI == 0) {
          obf[(size_t)m * N + n] = f2bf(acc[mt][nt][i] + bias[n] * bmul);
        } else if constexpr (EPI == 2) {
          obf[(size_t)m * N + n] = f2bf(fmaxf(acc[mt][nt][i] + bias[n], 0.0f));
        } else if constexpr (EPI == 4) {
          if (wr) {
            const float v = acc[mt][nt][i] + bias[n] + bf2f(resid[((size_t)m << 8) + n]);
            obf[(r2 << 8) + n] = f2bf(v);
          }
        }
      }
    }
}

__global__ __launch_bounds__(256) void gemm_qkv(
    const ushort* A, const ushort* Bt, const float* bq, const float* bk, const float* bv,
    ushort* Q, ushort* K, ushort* V) {
  gemm_a_body<0>(A, Bt, 256, 256, bq, bk, bv, Q, K, V, nullptr, nullptr);
}
__global__ __launch_bounds__(256) void gemm_ffn1(
    const ushort* A, const ushort* Bt, const float* b1, ushort* t16) {
  gemm_a_body<2>(A, Bt, 512, 256, b1, nullptr, nullptr, t16, nullptr, nullptr,
                 nullptr, nullptr);
}
__global__ __launch_bounds__(256) void gemm_wo(
    const ushort* A, const ushort* Bt, const float* bo,
    ushort* hpre16, const ushort* resid, const int* start) {
  gemm_a_body<4>(A, Bt, 256, 256, bo, nullptr, nullptr, hpre16, nullptr, nullptr,
                 resid, start);
}

// ============ GEMM variant NL: LDS-free, barrier-free (weight B is L2-resident) ============
// 128x128 tile, 4 waves, 256 thr. A and B fragments stream global->VGPR; K is a
// compile-time constant so the K/32-step loop fully unrolls and the compiler
// pipelines loads across MFMAs with counted vmcnt (no barrier drain at all).
// EPI 5: +bias + bf16 resid -> fp32;  EPI 6: +bias + bf16 resid -> bf16
template<int EPI, int K>
__device__ __forceinline__ void gemm_nl_body(
    const ushort* __restrict__ A, const ushort* __restrict__ Bt,
    const float* __restrict__ bias,
    ushort* __restrict__ o16, float* __restrict__ of32,
    const ushort* __restrict__ resid) {
  const int tid = threadIdx.x, lane = tid & 63, wid = tid >> 6;
  const int hi = lane >> 4, lc = lane & 15;
  const int wm = wid >> 1, wn = wid & 1;

  const uint nx = gridDim.x, ny = gridDim.y;
  const uint hwid = blockIdx.y * nx + blockIdx.x;
  const uint wg = xcd_swz(hwid, nx * ny);
  const int bx = wg / ny, by = wg % ny;
  const int m0 = bx * 128, ncol0 = by * 128;

  // per-wave row base pointers (k-offsets fold into imm offsets after unroll)
  const ushort* arow[4];
  const ushort* brow[4];
#pragma unroll
  for (int t = 0; t < 4; ++t) {
    arow[t] = A + (size_t)(m0 + wm * 64 + t * 16 + lc) * K + hi * 8;
    brow[t] = Bt + (size_t)(ncol0 + wn * 64 + t * 16 + lc) * K + hi * 8;
  }

  f32x4 acc[4][4];
#pragma unroll
  for (int a = 0; a < 4; ++a)
#pragma unroll
    for (int b = 0; b < 4; ++b) acc[a][b] = (f32x4)0.0f;

#pragma unroll
  for (int s = 0; s < K / 32; ++s) {
    short8 af[4], bfr[4];
#pragma unroll
    for (int t = 0; t < 4; ++t) {
      af[t] = *(const short8*)(arow[t] + s * 32);
      bfr[t] = *(const short8*)(brow[t] + s * 32);
    }
#pragma unroll
    for (int mt = 0; mt < 4; ++mt)
#pragma unroll
      for (int nt = 0; nt < 4; ++nt)
        acc[mt][nt] = __builtin_amdgcn_mfma_f32_16x16x32_bf16(af[mt], bfr[nt], acc[mt][nt], 0, 0, 0);
  }

#pragma unroll
  for (int mt = 0; mt < 4; ++mt)
#pragma unroll
    for (int i = 0; i < 4; ++i) {
      const int m = m0 + wm * 64 + mt * 16 + hi * 4 + i;
#pragma unroll
      for (int nt = 0; nt < 4; ++nt) {
        const int n = ncol0 + wn * 64 + nt * 16 + lc;
        const float v = acc[mt][nt][i] + bias[n] + bf2f(resid[((size_t)m << 8) + n]);
        if constexpr (EPI == 6) o16[((size_t)m << 8) + n] = f2bf(v);
        else of32[((size_t)m << 8) + n] = v;
      }
    }
}

__global__ __launch_bounds__(256) void gemm_ffn2_nl(
    const ushort* A, const ushort* Bt, const float* b2,
    float* out, const ushort* resid) {
  gemm_nl_body<5, 512>(A, Bt, b2, nullptr, out, resid);
}
__global__ __launch_bounds__(256) void gemm_ffn2b_nl(
    const ushort* A, const ushort* Bt, const float* b2,
    ushort* fh16, const ushort* resid) {
  gemm_nl_body<6, 512>(A, Bt, b2, fh16, nullptr, resid);
}

// ---------------- streaming row-LayerNorm (256 cols), 8 rows/block ----------------
template<int IN_BF, int OUT_BF>
__global__ __launch_bounds__(512) void ln_k(const void* __restrict__ in,
                                            const float* __restrict__ gamma,
                                            const float* __restrict__ beta,
                                            void* __restrict__ outp) {
  const int lane = threadIdx.x & 63, wid = threadIdx.x >> 6;
  const size_t r = (size_t)blockIdx.x * 8 + wid;
  float f[4];
  if constexpr (IN_BF) {
    const ushort4v v = *(const ushort4v*)((const ushort*)in + (r << 8) + lane * 4);
    f[0] = bf2f(v[0]); f[1] = bf2f(v[1]); f[2] = bf2f(v[2]); f[3] = bf2f(v[3]);
  } else {
    const float4 v = *(const float4*)((const float*)in + (r << 8) + lane * 4);
    f[0] = v.x; f[1] = v.y; f[2] = v.z; f[3] = v.w;
  }
  float s = (f[0] + f[1]) + (f[2] + f[3]);
  float ss = (f[0] * f[0] + f[1] * f[1]) + (f[2] * f[2] + f[3] * f[3]);
#pragma unroll
  for (int m = 1; m < 64; m <<= 1) {
    s += __shfl_xor(s, m); ss += __shfl_xor(ss, m);
  }
  const float mu = s * (1.0f / 256.0f);
  const float rs = rsqrtf(ss * (1.0f / 256.0f) - mu * mu + 1e-5f);
  const float4 gv = *(const float4*)(gamma + lane * 4);
  const float4 bv = *(const float4*)(beta + lane * 4);
  float o[4];
  o[0] = (f[0] - mu) * rs * gv.x + bv.x;
  o[1] = (f[1] - mu) * rs * gv.y + bv.y;
  o[2] = (f[2] - mu) * rs * gv.z + bv.z;
  o[3] = (f[3] - mu) * rs * gv.w + bv.w;
  if constexpr (OUT_BF) {
    ushort4v u;
    u[0] = f2bf(o[0]); u[1] = f2bf(o[1]); u[2] = f2bf(o[2]); u[3] = f2bf(o[3]);
    *(ushort4v*)((ushort*)outp + (r << 8) + lane * 4) = u;
  } else {
    float4 u; u.x = o[0]; u.y = o[1]; u.z = o[2]; u.w = o[3];
    *(float4*)((float*)outp + (r << 8) + lane * 4) = u;
  }
}

// ---------------- attention: one block per (g, head); O may alias Kb ----------------
// 8 waves. Masking baked into K/V staging; Q pre-scaled by log2e -> RAW v_exp_f32.
// qt-PAIR per wave iteration: one K/V fragment read feeds two MFMAs (halves
// ds_read traffic, 2 independent dep-chains). P via LDS, 5 windows of 64 cols.
#define KSTR 40
#define VSTR 296
#define PSTR 72    // 64-col window + pad; 144B rows, word-stride 20 mod 32
#define OSTR 40
__global__ __launch_bounds__(512) void attn_k(
    const ushort* __restrict__ Q, const ushort* Kb,
    const ushort* __restrict__ Vb, const int* __restrict__ start,
    ushort* O) {
  __shared__ __align__(16) ushort Ks[272 * KSTR];     // 21760 B
  __shared__ __align__(16) ushort Vt[32 * VSTR];      // 18944 B
  __shared__ __align__(16) ushort Pb[8][32 * PSTR];   // 36864 B (2 windows/wave; Ot overlays)
  const int tid = threadIdx.x, lane = tid & 63, wid = tid >> 6;
  const int hi = lane >> 4, lo = lane & 15;
  const uint wg = xcd_swz(blockIdx.x, 2048);   // h-siblings -> same XCD (share K/V lines)
  const int g = wg >> 3, h = wg & 7;
  const int cnt = start[g + 1] - start[g];
  const size_t base = ((size_t)g * 257) * 256 + h * 32;

  for (int n = tid; n < 272; n += 512) {
    const bool rv = (n < cnt) || (n == 256);
    if (n < 257 && rv) {
      const ushort* src = Kb + base + ((size_t)n << 8);
#pragma unroll
      for (int j = 0; j < 4; ++j)
        *(ushort8*)(Ks + n * KSTR + j * 8) = *(const ushort8*)(src + j * 8);
    } else {
      const ushort8 zz = (ushort8)0;
#pragma unroll
      for (int j = 0; j < 4; ++j) *(ushort8*)(Ks + n * KSTR + j * 8) = zz;
    }
  }
  // V^T staging: packed b32 writes, consecutive lanes -> consecutive n words
  for (int u = tid; u < 576; u += 512) {
    const int npair = u % 144;
    const int d0 = (u / 144) * 8;
    const int n0 = npair * 2;
    const bool rv0 = (n0 < cnt) || (n0 == 256);
    const bool rv1 = (n0 + 1 < cnt) || (n0 + 1 == 256);
    ushort8 a8 = (ushort8)0, b8 = (ushort8)0;
    if (n0 < 257 && rv0) a8 = *(const ushort8*)(Vb + base + ((size_t)n0 << 8) + d0);
    if (n0 + 1 < 257 && rv1) b8 = *(const ushort8*)(Vb + base + ((size_t)(n0 + 1) << 8) + d0);
#pragma unroll
    for (int j = 0; j < 8; ++j)
      *(uint*)(Vt + (d0 + j) * VSTR + n0) = (uint)a8[j] | ((uint)b8[j] << 16);
  }
  __syncthreads();

  for (int qp = wid; qp < 9; qp += 8) {
    const int qt0 = qp * 2, qt1 = qp * 2 + 1;   // qt1 may be 17 (dummy)
    const int qr0 = qt0 * 16 + lo, qr1 = qt1 * 16 + lo;
    const int qc0 = qr0 < 257 ? qr0 : 256;
    const int qc1 = qr1 < 257 ? qr1 : 256;
    const short8 qf0 = *(const short8*)(Q + base + ((size_t)qc0 << 8) + hi * 8);
    const short8 qf1 = *(const short8*)(Q + base + ((size_t)qc1 << 8) + hi * 8);
    ushort* Pw0 = Pb[wid];
    ushort* Pw1 = Pb[wid] + 16 * PSTR;

    float den0 = -(float)(271 - cnt);   // dead cols contribute exp2(0)=1 each
    float den1 = den0;
    f32x4 o00 = (f32x4)0.0f, o01 = (f32x4)0.0f;
    f32x4 o10 = (f32x4)0.0f, o11 = (f32x4)0.0f;

#pragma unroll
    for (int ph = 0; ph < 5; ++ph) {
      const int ktB = ph * 4;
      const int ktE = (ph * 4 + 4 < 17) ? ph * 4 + 4 : 17;
      const int nb = ph * 64;
      float dl0 = 0.f, dl1 = 0.f;
      // QK^T pair + raw exp2 + pack -> P windows
#pragma unroll
      for (int kt = ktB; kt < ktE; ++kt) {
        const short8 kf = *(const short8*)(Ks + (kt * 16 + lo) * KSTR + hi * 8);
        const f32x4 s0 = __builtin_amdgcn_mfma_f32_16x16x32_bf16(kf, qf0, (f32x4)0.0f, 0, 0, 0);
        const f32x4 s1 = __builtin_amdgcn_mfma_f32_16x16x32_bf16(kf, qf1, (f32x4)0.0f, 0, 0, 0);
        const float a0 = ex2(s0[0]), a1 = ex2(s0[1]), a2 = ex2(s0[2]), a3 = ex2(s0[3]);
        dl0 += (a0 + a1) + (a2 + a3);
        uint2v w0; w0[0] = cvtpk(a0, a1); w0[1] = cvtpk(a2, a3);
        *(uint2v*)(Pw0 + lo * PSTR + (kt * 16 + hi * 4 - nb)) = w0;
        const float b0 = ex2(s1[0]), b1 = ex2(s1[1]), b2 = ex2(s1[2]), b3 = ex2(s1[3]);
        dl1 += (b0 + b1) + (b2 + b3);
        uint2v w1; w1[0] = cvtpk(b0, b1); w1[1] = cvtpk(b2, b3);
        *(uint2v*)(Pw1 + lo * PSTR + (kt * 16 + hi * 4 - nb)) = w1;
      }
      den0 += dl0; den1 += dl1;
      if (ph == 4) {  // zero-pad n=272..287 (window-rel 16..31)
        uint2v z0; z0[0] = 0u; z0[1] = 0u;
        *(uint2v*)(Pw0 + lo * PSTR + (16 + hi * 4)) = z0;
        *(uint2v*)(Pw1 + lo * PSTR + (16 + hi * 4)) = z0;
      }
      asm volatile("s_waitcnt lgkmcnt(0)" ::: "memory");
      __builtin_amdgcn_sched_barrier(0);
      // PV over this window: one V-frag read feeds both q-tiles
      __builtin_amdgcn_s_setprio(1);
      const int ksB = ph * 2;
      const int ksE = (ph * 2 + 2 < 9) ? ph * 2 + 2 : 9;
#pragma unroll
      for (int ks = ksB; ks < ksE; ++ks) {
        const short8 va0 = *(const short8*)(Vt + lo * VSTR + ks * 32 + hi * 8);
        const short8 va1 = *(const short8*)(Vt + (16 + lo) * VSTR + ks * 32 + hi * 8);
        const short8 p0 = *(const short8*)(Pw0 + lo * PSTR + (ks * 32 + hi * 8 - nb));
        const short8 p1 = *(const short8*)(Pw1 + lo * PSTR + (ks * 32 + hi * 8 - nb));
        o00 = __builtin_amdgcn_mfma_f32_16x16x32_bf16(va0, p0, o00, 0, 0, 0);
        o01 = __builtin_amdgcn_mfma_f32_16x16x32_bf16(va1, p0, o01, 0, 0, 0);
        o10 = __builtin_amdgcn_mfma_f32_16x16x32_bf16(va0, p1, o10, 0, 0, 0);
        o11 = __builtin_amdgcn_mfma_f32_16x16x32_bf16(va1, p1, o11, 0, 0, 0);
      }
      __builtin_amdgcn_s_setprio(0);
      __builtin_amdgcn_sched_barrier(0);  // pin: next window's writes stay below these reads
    }

    den0 += __shfl_xor(den0, 16); den0 += __shfl_xor(den0, 32);
    den1 += __shfl_xor(den1, 16); den1 += __shfl_xor(den1, 32);
    const float inv0 = 1.0f / den0;
    const float inv1 = 1.0f / den1;

    // normalize, transpose via per-wave LDS overlays, store both q-tiles
    {
      const uint w0 = cvtpk(o00[0] * inv0, o00[1] * inv0);
      const uint w1 = cvtpk(o00[2] * inv0, o00[3] * inv0);
      const uint w2 = cvtpk(o01[0] * inv0, o01[1] * inv0);
      const uint w3 = cvtpk(o01[2] * inv0, o01[3] * inv0);
      ushort* ob = Pw0 + lo * OSTR + hi * 4;
      *(uint*)(ob + 0) = w0;
      *(uint*)(ob + 2) = w1;
      *(uint*)(ob + 16) = w2;
      *(uint*)(ob + 18) = w3;
      const uint x0 = cvtpk(o10[0] * inv1, o10[1] * inv1);
      const uint x1 = cvtpk(o10[2] * inv1, o10[3] * inv1);
      const uint x2 = cvtpk(o11[0] * inv1, o11[1] * inv1);
      const uint x3 = cvtpk(o11[2] * inv1, o11[3] * inv1);
      ushort* ob1 = Pw1 + lo * OSTR + hi * 4;
      *(uint*)(ob1 + 0) = x0;
      *(uint*)(ob1 + 2) = x1;
      *(uint*)(ob1 + 16) = x2;
      *(uint*)(ob1 + 18) = x3;
    }
    asm volatile("s_waitcnt lgkmcnt(0)" ::: "memory");
    __builtin_amdgcn_sched_barrier(0);
    {
      const int r = lane >> 2;
      const ushort8 ov0 = *(const ushort8*)(Pw0 + r * OSTR + (lane & 3) * 8);
      const int q20 = qt0 * 16 + r;
      if (q20 < 257)
        *(ushort8*)(O + base + ((size_t)q20 << 8) + (lane & 3) * 8) = ov0;
      const ushort8 ov1 = *(const ushort8*)(Pw1 + r * OSTR + (lane & 3) * 8);
      const int q21 = qt1 * 16 + r;
      if (q21 < 257)
        *(ushort8*)(O + base + ((size_t)q21 << 8) + (lane & 3) * 8) = ov1;
    }
    __builtin_amdgcn_sched_barrier(0);
  }
}

extern "C" void kernel_launch(void* const* d_in, const int* in_sizes, int n_in,
                              void* d_out, int out_size, void* d_ws, size_t ws_size,
                              hipStream_t stream) {
  (void)in_sizes; (void)n_in; (void)out_size;
  const float* x     = (const float*)d_in[0];
  const int*   batch = (const int*)d_in[1];
  const float* cls   = (const float*)d_in[2];
  const float* Wq    = (const float*)d_in[3];
  const float* bq    = (const float*)d_in[4];
  const float* Wk    = (const float*)d_in[5];
  const float* bk    = (const float*)d_in[6];
  const float* Wv    = (const float*)d_in[7];
  const float* bv    = (const float*)d_in[8];
  const float* Wo    = (const float*)d_in[9];
  const float* bo    = (const float*)d_in[10];
  const float* g0    = (const float*)d_in[11];
  const float* beta0 = (const float*)d_in[12];
  const float* W1    = (const float*)d_in[13];
  const float* b1    = (const float*)d_in[14];
  const float* W2    = (const float*)d_in[15];
  const float* b2    = (const float*)d_in[16];
  const float* g1    = (const float*)d_in[17];
  const float* beta1 = (const float*)d_in[18];

  // Workspace (base plan peak 102.1 MB; +33.7 MB fh16 if ws allows):
  //   S1 @0      : Q -> hpre16 (wo out, COMPACT rows) -> tmid (spans S1+S2)
  //   S2 @33.7MB : K -> attn O (dense) -> tmid (upper)
  //   S3 @67.4MB : V -> h16 (LN0 out, compact; ffn1 A AND ffn2 resid)
  //   S4 @101MB  : fh16 (ffn2 bf16 out) [only if ws_size >= 135.8MB]
  // d_out: xd (bf16 dense in; QKV A AND wo resid) -> final out
  char* ws = (char*)d_ws;
  int*    start = (int*)ws;
  ushort* Wt    = (ushort*)(ws + 4096);
  char*   sbase = ws + 1052672;
  ushort* Qb    = (ushort*)(sbase);
  ushort* Kb2   = (ushort*)(sbase + 33685504);
  ushort* Vb2   = (ushort*)(sbase + 67371008);
  ushort* fh16  = (ushort*)(sbase + 101056512);
  ushort* hpre16 = Qb;
  ushort* h16   = Vb2;
  ushort* tmid  = Qb;                       // 65792x512 bf16 spans S1+S2
  ushort* xd    = (ushort*)d_out;
  float*  out   = (float*)d_out;
  const bool big_ws = ws_size >= (size_t)135794688;

  seg_start_k<<<256, 256, 0, stream>>>(batch, start);
  prep_w_k<<<dim3(512, 6), 256, 0, stream>>>(Wq, Wk, Wv, Wo, W1, W2, Wt);
  pack_xd_k<<<8224, 256, 0, stream>>>(x, cls, start, xd);
  gemm_qkv<<<dim3(514, 6), 256, 0, stream>>>(xd, Wt, bq, bk, bv, Qb, Kb2, Vb2);
  attn_k<<<2048, 512, 0, stream>>>(Qb, Kb2, Vb2, start, Kb2);   // O over K slot
  gemm_wo<<<dim3(514, 2), 256, 0, stream>>>(Kb2, Wt + 196608, bo, hpre16, xd, start);
  ln_k<1, 1><<<8224, 512, 0, stream>>>(hpre16, g0, beta0, h16);
  gemm_ffn1<<<dim3(514, 4), 256, 0, stream>>>(h16, Wt + 262144, b1, tmid);
  if (big_ws) {
    gemm_ffn2b_nl<<<dim3(514, 2), 256, 0, stream>>>(tmid, Wt + 393216, b2, fh16, h16);
    ln_k<1, 0><<<8224, 512, 0, stream>>>(fh16, g1, beta1, out);
  } else {
    gemm_ffn2_nl<<<dim3(514, 2), 256, 0, stream>>>(tmid, Wt + 393216, b2, out, h16);
    ln_k<0, 0><<<8224, 512, 0, stream>>>(out, g1, beta1, out);
  }
}

// Round 18
// 258.621 us; speedup vs baseline: 1.1909x; 1.1909x over previous
//
#include <hip/hip_runtime.h>

typedef __attribute__((ext_vector_type(8))) short short8;    // bf16x8 MFMA frag
typedef __attribute__((ext_vector_type(8))) unsigned short ushort8;
typedef __attribute__((ext_vector_type(4))) unsigned short ushort4v;
typedef __attribute__((ext_vector_type(4))) float f32x4;
typedef __attribute__((ext_vector_type(2))) unsigned int uint2v;
typedef unsigned short ushort;
typedef unsigned int uint;

#define QS2F (0.17677669529663687f * 1.4426950408889634f) // 1/sqrt(32) * log2(e)

__device__ __forceinline__ ushort f2bf(float f) {
  union { float f; unsigned u; } a; a.f = f;
  unsigned r = a.u + 0x7fffu + ((a.u >> 16) & 1u);
  return (ushort)(r >> 16);
}
__device__ __forceinline__ float bf2f(ushort u) {
  union { uint u; float f; } a; a.u = ((uint)u) << 16; return a.f;
}
__device__ __forceinline__ uint cvtpk(float a, float b) {  // low16=bf(a), high16=bf(b)
  uint r; asm("v_cvt_pk_bf16_f32 %0, %1, %2" : "=v"(r) : "v"(a), "v"(b)); return r;
}
__device__ __forceinline__ float ex2(float x) {  // raw v_exp_f32 (2^x), single instr
  return __builtin_amdgcn_exp2f(x);
}

__device__ __forceinline__ void gload16(const void* g, void* l) {
  __builtin_amdgcn_global_load_lds((const __attribute__((address_space(1))) void*)g,
                                   (__attribute__((address_space(3))) void*)l, 16, 0, 0);
}

// bijective XCD swizzle (m204): hwid -> logical wg, chunked per XCD
__device__ __forceinline__ uint xcd_swz(uint hwid, uint nwg) {
  const uint q8 = nwg >> 3, r8 = nwg & 7;
  const uint xcd = hwid & 7, i8 = hwid >> 3;
  return (xcd < r8 ? xcd * (q8 + 1) : r8 * (q8 + 1) + (xcd - r8) * q8) + i8;
}

// ---------------- segment starts (batch sorted & contiguous) ----------------
__global__ __launch_bounds__(256) void seg_start_k(const int* __restrict__ batch,
                                                   int* __restrict__ start) {
  const int i = blockIdx.x * 256 + threadIdx.x;
  const int b = batch[i];
  if (i == 0 || batch[i - 1] != b) start[b] = i;
  if (i == 0) start[256] = 65536;
}

// ---------------- weight transpose + bf16 convert (Wq pre-scaled for exp2) ----------------
__global__ __launch_bounds__(256) void prep_w_k(
    const float* __restrict__ Wq, const float* __restrict__ Wk,
    const float* __restrict__ Wv, const float* __restrict__ Wo,
    const float* __restrict__ W1, const float* __restrict__ W2,
    ushort* __restrict__ Wt) {
  const int w = blockIdx.y;
  const float* src; ushort* dst; int Kd, Nd; float sc = 1.0f;
  switch (w) {
    case 0: src = Wq; dst = Wt;          Kd = 256; Nd = 256; sc = QS2F; break;
    case 1: src = Wk; dst = Wt + 65536;  Kd = 256; Nd = 256; break;
    case 2: src = Wv; dst = Wt + 131072; Kd = 256; Nd = 256; break;
    case 3: src = Wo; dst = Wt + 196608; Kd = 256; Nd = 256; break;
    case 4: src = W1; dst = Wt + 262144; Kd = 256; Nd = 512; break;
    default: src = W2; dst = Wt + 393216; Kd = 512; Nd = 256; break;
  }
  const int e = blockIdx.x * 256 + threadIdx.x;
  if (e < Kd * Nd) {
    const int k = e / Nd, n = e - k * Nd;
    dst[n * Kd + k] = f2bf(src[e] * sc);
  }
}

// ---------------- pack x -> dense bf16 [G*257][256] ----------------
__global__ __launch_bounds__(256) void pack_xd_k(
    const float* __restrict__ x, const float* __restrict__ cls,
    const int* __restrict__ start, ushort* __restrict__ xd) {
  const size_t idx = (((size_t)blockIdx.x << 8) + threadIdx.x) << 3;  // 8 cols/thread
  const int row = (int)(idx >> 8);
  const int col = (int)(idx & 255);
  const int g = row / 257, n = row - g * 257;
  const int sg = start[g], cn = start[g + 1] - sg;
  float4 a, b;
  if (n < cn) {
    const float* src = x + (((size_t)(sg + n)) << 8) + col;
    a = ((const float4*)src)[0]; b = ((const float4*)src)[1];
  } else if (n == 256) {
    const float* src = cls + (((size_t)g) << 8) + col;
    a = ((const float4*)src)[0]; b = ((const float4*)src)[1];
  } else {
    a.x = a.y = a.z = a.w = 0.f; b = a;
  }
  ushort8 o;
  o[0] = f2bf(a.x); o[1] = f2bf(a.y); o[2] = f2bf(a.z); o[3] = f2bf(a.w);
  o[4] = f2bf(b.x); o[5] = f2bf(b.y); o[6] = f2bf(b.z); o[7] = f2bf(b.w);
  *(ushort8*)(xd + idx) = o;
}

// ============ GEMM variant A: 128x128 tile, 4 waves, 256 thr, single-buf 32KB ============
// EPI 0: +bias -> bf16 (by encodes (z, n-half) for fused QKV; Q bias scaled by QS2F)
// EPI 2: relu(+bias) -> bf16 (by = n-block of N)
// EPI 4: +bias + bf16 resid(dense m) -> bf16 SCATTERED to compact row r2
// EPI 5: +bias + bf16 resid -> fp32 (same-layout rows)
// EPI 6: +bias + bf16 resid -> bf16 (same-layout rows)
template<int EPI>
__device__ __forceinline__ void gemm_a_body(
    const ushort* __restrict__ A, const ushort* __restrict__ Bt,
    int N, int K,
    const float* __restrict__ b0, const float* __restrict__ b1, const float* __restrict__ b2,
    ushort* __restrict__ o0, ushort* __restrict__ o1, ushort* __restrict__ o2,
    float* __restrict__ of32, const ushort* __restrict__ resid,
    const int* __restrict__ start) {
  __shared__ __align__(16) char As[16384];  // 128 x 128B, XOR-swizzled
  __shared__ __align__(16) char Bs[16384];
  const int tid = threadIdx.x, lane = tid & 63, wid = tid >> 6;
  const int hi = lane >> 4, lc = lane & 15;
  const int wm = wid >> 1, wn = wid & 1;

  const uint nx = gridDim.x, ny = gridDim.y;
  const uint hwid = blockIdx.y * nx + blockIdx.x;
  const uint wg = xcd_swz(hwid, nx * ny);
  const int bx = wg / ny, by = wg % ny;

  const int m0 = bx * 128;
  const int z = (EPI == 0) ? (by >> 1) : 0;
  const int ncol0 = (EPI == 0) ? (by & 1) * 128 : by * 128;
  const ushort* Bz = (EPI == 0) ? Bt + (size_t)z * 65536 : Bt;
  const float* bias = (EPI == 0) ? (z == 0 ? b0 : (z == 1 ? b1 : b2)) : b0;
  const float bmul = (EPI == 0 && z == 0) ? QS2F : 1.0f;
  ushort* obf = (EPI == 0) ? (z == 0 ? o0 : (z == 1 ? o1 : o2)) : o0;

  f32x4 acc[4][4];
#pragma unroll
  for (int a = 0; a < 4; ++a)
#pragma unroll
    for (int b = 0; b < 4; ++b) acc[a][b] = (f32x4)0.0f;

  for (int kt = 0; kt < K; kt += 64) {
#pragma unroll
    for (int r = 0; r < 4; ++r) {
      const int L = (r * 256 + tid) * 16;
      const int row = L >> 7;
      const int cb = (L & 127) ^ ((row & 7) << 4);
      gload16(A + (size_t)(m0 + row) * K + kt + (cb >> 1), As + L);
    }
#pragma unroll
    for (int r = 0; r < 4; ++r) {
      const int L = (r * 256 + tid) * 16;
      const int row = L >> 7;
      const int cb = (L & 127) ^ ((row & 7) << 4);
      gload16(Bz + (size_t)(ncol0 + row) * K + kt + (cb >> 1), Bs + L);
    }
    asm volatile("s_waitcnt vmcnt(0)" ::: "memory");
    __syncthreads();
#pragma unroll
    for (int ks = 0; ks < 2; ++ks) {
      short8 af[4], bfr[4];
      const int cB = (ks * 32 + hi * 8) * 2;
#pragma unroll
      for (int t = 0; t < 4; ++t) {
        const int rA = wm * 64 + t * 16 + lc;
        af[t] = *(const short8*)(As + (rA << 7) + (cB ^ ((rA & 7) << 4)));
        const int rB = wn * 64 + t * 16 + lc;
        bfr[t] = *(const short8*)(Bs + (rB << 7) + (cB ^ ((rB & 7) << 4)));
      }
#pragma unroll
      for (int mt = 0; mt < 4; ++mt)
#pragma unroll
        for (int nt = 0; nt < 4; ++nt)
          acc[mt][nt] = __builtin_amdgcn_mfma_f32_16x16x32_bf16(af[mt], bfr[nt], acc[mt][nt], 0, 0, 0);
    }
    __syncthreads();
  }

#pragma unroll
  for (int mt = 0; mt < 4; ++mt)
#pragma unroll
    for (int i = 0; i < 4; ++i) {
      const int m = m0 + wm * 64 + mt * 16 + hi * 4 + i;
      size_t r2 = (size_t)m;
      bool wr = true;
      if constexpr (EPI == 4) {
        // dense row m -> compact row r2 (nodes in x-order, then CLS block)
        const int gg = m / 257, nr = m - gg * 257;
        const int sg = start[gg], cn = start[gg + 1] - sg;
        if (nr < cn) r2 = (size_t)(sg + nr);
        else if (nr == 256) r2 = (size_t)(65536 + gg);
        else wr = false;
      }
#pragma unroll
      for (int nt = 0; nt < 4; ++nt) {
        const int n = ncol0 + wn * 64 + nt * 16 + lc;
        if constexpr (EPI == 0) {
          obf[(size_t)m * N + n] = f2bf(acc[mt][nt][i] + bias[n] * bmul);
        } else if constexpr (EPI == 2) {
          obf[(size_t)m * N + n] = f2bf(fmaxf(acc[mt][nt][i] + bias[n], 0.0f));
        } else if constexpr (EPI == 4) {
          if (wr) {
            const float v = acc[mt][nt][i] + bias[n] + bf2f(resid[((size_t)m << 8) + n]);
            obf[(r2 << 8) + n] = f2bf(v);
          }
        } else {
          const float v = acc[mt][nt][i] + bias[n] + bf2f(resid[((size_t)m << 8) + n]);
          if constexpr (EPI == 6) obf[((size_t)m << 8) + n] = f2bf(v);
          else of32[((size_t)m << 8) + n] = v;
        }
      }
    }
}

__global__ __launch_bounds__(256) void gemm_qkv(
    const ushort* A, const ushort* Bt, const float* bq, const float* bk, const float* bv,
    ushort* Q, ushort* K, ushort* V) {
  gemm_a_body<0>(A, Bt, 256, 256, bq, bk, bv, Q, K, V, nullptr, nullptr, nullptr);
}
__global__ __launch_bounds__(256) void gemm_ffn1(
    const ushort* A, const ushort* Bt, const float* b1, ushort* t16) {
  gemm_a_body<2>(A, Bt, 512, 256, b1, nullptr, nullptr, t16, nullptr, nullptr,
                 nullptr, nullptr, nullptr);
}
__global__ __launch_bounds__(256) void gemm_wo(
    const ushort* A, const ushort* Bt, const float* bo,
    ushort* hpre16, const ushort* resid, const int* start) {
  gemm_a_body<4>(A, Bt, 256, 256, bo, nullptr, nullptr, hpre16, nullptr, nullptr,
                 nullptr, resid, start);
}
__global__ __launch_bounds__(256) void gemm_ffn2(
    const ushort* A, const ushort* Bt, const float* b2,
    float* out, const ushort* resid) {
  gemm_a_body<5>(A, Bt, 256, 512, b2, nullptr, nullptr, nullptr, nullptr, nullptr,
                 out, resid, nullptr);
}
__global__ __launch_bounds__(256) void gemm_ffn2b(
    const ushort* A, const ushort* Bt, const float* b2,
    ushort* fh16, const ushort* resid) {
  gemm_a_body<6>(A, Bt, 256, 512, b2, nullptr, nullptr, fh16, nullptr, nullptr,
                 nullptr, resid, nullptr);
}

// ---------------- streaming row-LayerNorm (256 cols), 8 rows/block ----------------
template<int IN_BF, int OUT_BF>
__global__ __launch_bounds__(512) void ln_k(const void* __restrict__ in,
                                            const float* __restrict__ gamma,
                                            const float* __restrict__ beta,
                                            void* __restrict__ outp) {
  const int lane = threadIdx.x & 63, wid = threadIdx.x >> 6;
  const size_t r = (size_t)blockIdx.x * 8 + wid;
  float f[4];
  if constexpr (IN_BF) {
    const ushort4v v = *(const ushort4v*)((const ushort*)in + (r << 8) + lane * 4);
    f[0] = bf2f(v[0]); f[1] = bf2f(v[1]); f[2] = bf2f(v[2]); f[3] = bf2f(v[3]);
  } else {
    const float4 v = *(const float4*)((const float*)in + (r << 8) + lane * 4);
    f[0] = v.x; f[1] = v.y; f[2] = v.z; f[3] = v.w;
  }
  float s = (f[0] + f[1]) + (f[2] + f[3]);
  float ss = (f[0] * f[0] + f[1] * f[1]) + (f[2] * f[2] + f[3] * f[3]);
#pragma unroll
  for (int m = 1; m < 64; m <<= 1) {
    s += __shfl_xor(s, m); ss += __shfl_xor(ss, m);
  }
  const float mu = s * (1.0f / 256.0f);
  const float rs = rsqrtf(ss * (1.0f / 256.0f) - mu * mu + 1e-5f);
  const float4 gv = *(const float4*)(gamma + lane * 4);
  const float4 bv = *(const float4*)(beta + lane * 4);
  float o[4];
  o[0] = (f[0] - mu) * rs * gv.x + bv.x;
  o[1] = (f[1] - mu) * rs * gv.y + bv.y;
  o[2] = (f[2] - mu) * rs * gv.z + bv.z;
  o[3] = (f[3] - mu) * rs * gv.w + bv.w;
  if constexpr (OUT_BF) {
    ushort4v u;
    u[0] = f2bf(o[0]); u[1] = f2bf(o[1]); u[2] = f2bf(o[2]); u[3] = f2bf(o[3]);
    *(ushort4v*)((ushort*)outp + (r << 8) + lane * 4) = u;
  } else {
    float4 u; u.x = o[0]; u.y = o[1]; u.z = o[2]; u.w = o[3];
    *(float4*)((float*)outp + (r << 8) + lane * 4) = u;
  }
}

// ---------------- attention: one block per (g, head); O may alias Kb ----------------
// 8 waves. Masking baked into K/V staging; Q pre-scaled by log2e -> RAW v_exp_f32.
// qt-PAIR per wave iteration: one K/V fragment read feeds two MFMAs (halves
// ds_read traffic, 2 independent dep-chains). P via LDS, 5 windows of 64 cols.
#define KSTR 40
#define VSTR 296
#define PSTR 72    // 64-col window + pad; 144B rows, word-stride 20 mod 32
#define OSTR 40
__global__ __launch_bounds__(512) void attn_k(
    const ushort* __restrict__ Q, const ushort* Kb,
    const ushort* __restrict__ Vb, const int* __restrict__ start,
    ushort* O) {
  __shared__ __align__(16) ushort Ks[272 * KSTR];     // 21760 B
  __shared__ __align__(16) ushort Vt[32 * VSTR];      // 18944 B
  __shared__ __align__(16) ushort Pb[8][32 * PSTR];   // 36864 B (2 windows/wave; Ot overlays)
  const int tid = threadIdx.x, lane = tid & 63, wid = tid >> 6;
  const int hi = lane >> 4, lo = lane & 15;
  const uint wg = xcd_swz(blockIdx.x, 2048);   // h-siblings -> same XCD (share K/V lines)
  const int g = wg >> 3, h = wg & 7;
  const int cnt = start[g + 1] - start[g];
  const size_t base = ((size_t)g * 257) * 256 + h * 32;

  for (int n = tid; n < 272; n += 512) {
    const bool rv = (n < cnt) || (n == 256);
    if (n < 257 && rv) {
      const ushort* src = Kb + base + ((size_t)n << 8);
#pragma unroll
      for (int j = 0; j < 4; ++j)
        *(ushort8*)(Ks + n * KSTR + j * 8) = *(const ushort8*)(src + j * 8);
    } else {
      const ushort8 zz = (ushort8)0;
#pragma unroll
      for (int j = 0; j < 4; ++j) *(ushort8*)(Ks + n * KSTR + j * 8) = zz;
    }
  }
  // V^T staging: packed b32 writes, consecutive lanes -> consecutive n words
  for (int u = tid; u < 576; u += 512) {
    const int npair = u % 144;
    const int d0 = (u / 144) * 8;
    const int n0 = npair * 2;
    const bool rv0 = (n0 < cnt) || (n0 == 256);
    const bool rv1 = (n0 + 1 < cnt) || (n0 + 1 == 256);
    ushort8 a8 = (ushort8)0, b8 = (ushort8)0;
    if (n0 < 257 && rv0) a8 = *(const ushort8*)(Vb + base + ((size_t)n0 << 8) + d0);
    if (n0 + 1 < 257 && rv1) b8 = *(const ushort8*)(Vb + base + ((size_t)(n0 + 1) << 8) + d0);
#pragma unroll
    for (int j = 0; j < 8; ++j)
      *(uint*)(Vt + (d0 + j) * VSTR + n0) = (uint)a8[j] | ((uint)b8[j] << 16);
  }
  __syncthreads();

  for (int qp = wid; qp < 9; qp += 8) {
    const int qt0 = qp * 2, qt1 = qp * 2 + 1;   // qt1 may be 17 (dummy)
    const int qr0 = qt0 * 16 + lo, qr1 = qt1 * 16 + lo;
    const int qc0 = qr0 < 257 ? qr0 : 256;
    const int qc1 = qr1 < 257 ? qr1 : 256;
    const short8 qf0 = *(const short8*)(Q + base + ((size_t)qc0 << 8) + hi * 8);
    const short8 qf1 = *(const short8*)(Q + base + ((size_t)qc1 << 8) + hi * 8);
    ushort* Pw0 = Pb[wid];
    ushort* Pw1 = Pb[wid] + 16 * PSTR;

    float den0 = -(float)(271 - cnt);   // dead cols contribute exp2(0)=1 each
    float den1 = den0;
    f32x4 o00 = (f32x4)0.0f, o01 = (f32x4)0.0f;
    f32x4 o10 = (f32x4)0.0f, o11 = (f32x4)0.0f;

#pragma unroll
    for (int ph = 0; ph < 5; ++ph) {
      const int ktB = ph * 4;
      const int ktE = (ph * 4 + 4 < 17) ? ph * 4 + 4 : 17;
      const int nb = ph * 64;
      float dl0 = 0.f, dl1 = 0.f;
      // QK^T pair + raw exp2 + pack -> P windows
#pragma unroll
      for (int kt = ktB; kt < ktE; ++kt) {
        const short8 kf = *(const short8*)(Ks + (kt * 16 + lo) * KSTR + hi * 8);
        const f32x4 s0 = __builtin_amdgcn_mfma_f32_16x16x32_bf16(kf, qf0, (f32x4)0.0f, 0, 0, 0);
        const f32x4 s1 = __builtin_amdgcn_mfma_f32_16x16x32_bf16(kf, qf1, (f32x4)0.0f, 0, 0, 0);
        const float a0 = ex2(s0[0]), a1 = ex2(s0[1]), a2 = ex2(s0[2]), a3 = ex2(s0[3]);
        dl0 += (a0 + a1) + (a2 + a3);
        uint2v w0; w0[0] = cvtpk(a0, a1); w0[1] = cvtpk(a2, a3);
        *(uint2v*)(Pw0 + lo * PSTR + (kt * 16 + hi * 4 - nb)) = w0;
        const float b0 = ex2(s1[0]), b1 = ex2(s1[1]), b2 = ex2(s1[2]), b3 = ex2(s1[3]);
        dl1 += (b0 + b1) + (b2 + b3);
        uint2v w1; w1[0] = cvtpk(b0, b1); w1[1] = cvtpk(b2, b3);
        *(uint2v*)(Pw1 + lo * PSTR + (kt * 16 + hi * 4 - nb)) = w1;
      }
      den0 += dl0; den1 += dl1;
      if (ph == 4) {  // zero-pad n=272..287 (window-rel 16..31)
        uint2v z0; z0[0] = 0u; z0[1] = 0u;
        *(uint2v*)(Pw0 + lo * PSTR + (16 + hi * 4)) = z0;
        *(uint2v*)(Pw1 + lo * PSTR + (16 + hi * 4)) = z0;
      }
      asm volatile("s_waitcnt lgkmcnt(0)" ::: "memory");
      __builtin_amdgcn_sched_barrier(0);
      // PV over this window: one V-frag read feeds both q-tiles
      __builtin_amdgcn_s_setprio(1);
      const int ksB = ph * 2;
      const int ksE = (ph * 2 + 2 < 9) ? ph * 2 + 2 : 9;
#pragma unroll
      for (int ks = ksB; ks < ksE; ++ks) {
        const short8 va0 = *(const short8*)(Vt + lo * VSTR + ks * 32 + hi * 8);
        const short8 va1 = *(const short8*)(Vt + (16 + lo) * VSTR + ks * 32 + hi * 8);
        const short8 p0 = *(const short8*)(Pw0 + lo * PSTR + (ks * 32 + hi * 8 - nb));
        const short8 p1 = *(const short8*)(Pw1 + lo * PSTR + (ks * 32 + hi * 8 - nb));
        o00 = __builtin_amdgcn_mfma_f32_16x16x32_bf16(va0, p0, o00, 0, 0, 0);
        o01 = __builtin_amdgcn_mfma_f32_16x16x32_bf16(va1, p0, o01, 0, 0, 0);
        o10 = __builtin_amdgcn_mfma_f32_16x16x32_bf16(va0, p1, o10, 0, 0, 0);
        o11 = __builtin_amdgcn_mfma_f32_16x16x32_bf16(va1, p1, o11, 0, 0, 0);
      }
      __builtin_amdgcn_s_setprio(0);
      __builtin_amdgcn_sched_barrier(0);  // pin: next window's writes stay below these reads
    }

    den0 += __shfl_xor(den0, 16); den0 += __shfl_xor(den0, 32);
    den1 += __shfl_xor(den1, 16); den1 += __shfl_xor(den1, 32);
    const float inv0 = 1.0f / den0;
    const float inv1 = 1.0f / den1;

    // normalize, transpose via per-wave LDS overlays, store both q-tiles
    {
      const uint w0 = cvtpk(o00[0] * inv0, o00[1] * inv0);
      const uint w1 = cvtpk(o00[2] * inv0, o00[3] * inv0);
      const uint w2 = cvtpk(o01[0] * inv0, o01[1] * inv0);
      const uint w3 = cvtpk(o01[2] * inv0, o01[3] * inv0);
      ushort* ob = Pw0 + lo * OSTR + hi * 4;
      *(uint*)(ob + 0) = w0;
      *(uint*)(ob + 2) = w1;
      *(uint*)(ob + 16) = w2;
      *(uint*)(ob + 18) = w3;
      const uint x0 = cvtpk(o10[0] * inv1, o10[1] * inv1);
      const uint x1 = cvtpk(o10[2] * inv1, o10[3] * inv1);
      const uint x2 = cvtpk(o11[0] * inv1, o11[1] * inv1);
      const uint x3 = cvtpk(o11[2] * inv1, o11[3] * inv1);
      ushort* ob1 = Pw1 + lo * OSTR + hi * 4;
      *(uint*)(ob1 + 0) = x0;
      *(uint*)(ob1 + 2) = x1;
      *(uint*)(ob1 + 16) = x2;
      *(uint*)(ob1 + 18) = x3;
    }
    asm volatile("s_waitcnt lgkmcnt(0)" ::: "memory");
    __builtin_amdgcn_sched_barrier(0);
    {
      const int r = lane >> 2;
      const ushort8 ov0 = *(const ushort8*)(Pw0 + r * OSTR + (lane & 3) * 8);
      const int q20 = qt0 * 16 + r;
      if (q20 < 257)
        *(ushort8*)(O + base + ((size_t)q20 << 8) + (lane & 3) * 8) = ov0;
      const ushort8 ov1 = *(const ushort8*)(Pw1 + r * OSTR + (lane & 3) * 8);
      const int q21 = qt1 * 16 + r;
      if (q21 < 257)
        *(ushort8*)(O + base + ((size_t)q21 << 8) + (lane & 3) * 8) = ov1;
    }
    __builtin_amdgcn_sched_barrier(0);
  }
}

extern "C" void kernel_launch(void* const* d_in, const int* in_sizes, int n_in,
                              void* d_out, int out_size, void* d_ws, size_t ws_size,
                              hipStream_t stream) {
  (void)in_sizes; (void)n_in; (void)out_size;
  const float* x     = (const float*)d_in[0];
  const int*   batch = (const int*)d_in[1];
  const float* cls   = (const float*)d_in[2];
  const float* Wq    = (const float*)d_in[3];
  const float* bq    = (const float*)d_in[4];
  const float* Wk    = (const float*)d_in[5];
  const float* bk    = (const float*)d_in[6];
  const float* Wv    = (const float*)d_in[7];
  const float* bv    = (const float*)d_in[8];
  const float* Wo    = (const float*)d_in[9];
  const float* bo    = (const float*)d_in[10];
  const float* g0    = (const float*)d_in[11];
  const float* beta0 = (const float*)d_in[12];
  const float* W1    = (const float*)d_in[13];
  const float* b1    = (const float*)d_in[14];
  const float* W2    = (const float*)d_in[15];
  const float* b2    = (const float*)d_in[16];
  const float* g1    = (const float*)d_in[17];
  const float* beta1 = (const float*)d_in[18];

  // Workspace (base plan peak 102.1 MB; +33.7 MB fh16 if ws allows):
  //   S1 @0      : Q -> hpre16 (wo out, COMPACT rows) -> tmid (spans S1+S2)
  //   S2 @33.7MB : K -> attn O (dense) -> tmid (upper)
  //   S3 @67.4MB : V -> h16 (LN0 out, compact; ffn1 A AND ffn2 resid)
  //   S4 @101MB  : fh16 (ffn2 bf16 out) [only if ws_size >= 135.8MB]
  // d_out: xd (bf16 dense in; QKV A AND wo resid) -> final out
  char* ws = (char*)d_ws;
  int*    start = (int*)ws;
  ushort* Wt    = (ushort*)(ws + 4096);
  char*   sbase = ws + 1052672;
  ushort* Qb    = (ushort*)(sbase);
  ushort* Kb2   = (ushort*)(sbase + 33685504);
  ushort* Vb2   = (ushort*)(sbase + 67371008);
  ushort* fh16  = (ushort*)(sbase + 101056512);
  ushort* hpre16 = Qb;
  ushort* h16   = Vb2;
  ushort* tmid  = Qb;                       // 65792x512 bf16 spans S1+S2
  ushort* xd    = (ushort*)d_out;
  float*  out   = (float*)d_out;
  const bool big_ws = ws_size >= (size_t)135794688;

  seg_start_k<<<256, 256, 0, stream>>>(batch, start);
  prep_w_k<<<dim3(512, 6), 256, 0, stream>>>(Wq, Wk, Wv, Wo, W1, W2, Wt);
  pack_xd_k<<<8224, 256, 0, stream>>>(x, cls, start, xd);
  gemm_qkv<<<dim3(514, 6), 256, 0, stream>>>(xd, Wt, bq, bk, bv, Qb, Kb2, Vb2);
  attn_k<<<2048, 512, 0, stream>>>(Qb, Kb2, Vb2, start, Kb2);   // O over K slot
  gemm_wo<<<dim3(514, 2), 256, 0, stream>>>(Kb2, Wt + 196608, bo, hpre16, xd, start);
  ln_k<1, 1><<<8224, 512, 0, stream>>>(hpre16, g0, beta0, h16);
  gemm_ffn1<<<dim3(514, 4), 256, 0, stream>>>(h16, Wt + 262144, b1, tmid);
  if (big_ws) {
    gemm_ffn2b<<<dim3(514, 2), 256, 0, stream>>>(tmid, Wt + 393216, b2, fh16, h16);
    ln_k<1, 0><<<8224, 512, 0, stream>>>(fh16, g1, beta1, out);
  } else {
    gemm_ffn2<<<dim3(514, 2), 256, 0, stream>>>(tmid, Wt + 393216, b2, out, h16);
    ln_k<0, 0><<<8224, 512, 0, stream>>>(out, g1, beta1, out);
  }
}

// Round 19
// 247.482 us; speedup vs baseline: 1.2445x; 1.0450x over previous
//
#include <hip/hip_runtime.h>

typedef __attribute__((ext_vector_type(8))) short short8;    // bf16x8 MFMA frag
typedef __attribute__((ext_vector_type(8))) unsigned short ushort8;
typedef __attribute__((ext_vector_type(4))) unsigned short ushort4v;
typedef __attribute__((ext_vector_type(4))) float f32x4;
typedef __attribute__((ext_vector_type(2))) unsigned int uint2v;
typedef unsigned short ushort;
typedef unsigned int uint;

#define QS2F (0.17677669529663687f * 1.4426950408889634f) // 1/sqrt(32) * log2(e)

__device__ __forceinline__ ushort f2bf(float f) {
  union { float f; unsigned u; } a; a.f = f;
  unsigned r = a.u + 0x7fffu + ((a.u >> 16) & 1u);
  return (ushort)(r >> 16);
}
__device__ __forceinline__ float bf2f(ushort u) {
  union { uint u; float f; } a; a.u = ((uint)u) << 16; return a.f;
}
__device__ __forceinline__ uint cvtpk(float a, float b) {  // low16=bf(a), high16=bf(b)
  uint r; asm("v_cvt_pk_bf16_f32 %0, %1, %2" : "=v"(r) : "v"(a), "v"(b)); return r;
}
__device__ __forceinline__ float ex2(float x) {  // raw v_exp_f32 (2^x), single instr
  return __builtin_amdgcn_exp2f(x);
}

__device__ __forceinline__ void gload16(const void* g, void* l) {
  __builtin_amdgcn_global_load_lds((const __attribute__((address_space(1))) void*)g,
                                   (__attribute__((address_space(3))) void*)l, 16, 0, 0);
}

// bijective XCD swizzle (m204): hwid -> logical wg, chunked per XCD
__device__ __forceinline__ uint xcd_swz(uint hwid, uint nwg) {
  const uint q8 = nwg >> 3, r8 = nwg & 7;
  const uint xcd = hwid & 7, i8 = hwid >> 3;
  return (xcd < r8 ? xcd * (q8 + 1) : r8 * (q8 + 1) + (xcd - r8) * q8) + i8;
}

// ---------------- segment starts (batch sorted & contiguous) ----------------
__global__ __launch_bounds__(256) void seg_start_k(const int* __restrict__ batch,
                                                   int* __restrict__ start) {
  const int i = blockIdx.x * 256 + threadIdx.x;
  const int b = batch[i];
  if (i == 0 || batch[i - 1] != b) start[b] = i;
  if (i == 0) start[256] = 65536;
}

// ---------------- weight transpose + bf16 convert (Wq pre-scaled for exp2) ----------------
__global__ __launch_bounds__(256) void prep_w_k(
    const float* __restrict__ Wq, const float* __restrict__ Wk,
    const float* __restrict__ Wv, const float* __restrict__ Wo,
    const float* __restrict__ W1, const float* __restrict__ W2,
    ushort* __restrict__ Wt) {
  const int w = blockIdx.y;
  const float* src; ushort* dst; int Kd, Nd; float sc = 1.0f;
  switch (w) {
    case 0: src = Wq; dst = Wt;          Kd = 256; Nd = 256; sc = QS2F; break;
    case 1: src = Wk; dst = Wt + 65536;  Kd = 256; Nd = 256; break;
    case 2: src = Wv; dst = Wt + 131072; Kd = 256; Nd = 256; break;
    case 3: src = Wo; dst = Wt + 196608; Kd = 256; Nd = 256; break;
    case 4: src = W1; dst = Wt + 262144; Kd = 256; Nd = 512; break;
    default: src = W2; dst = Wt + 393216; Kd = 512; Nd = 256; break;
  }
  const int e = blockIdx.x * 256 + threadIdx.x;
  if (e < Kd * Nd) {
    const int k = e / Nd, n = e - k * Nd;
    dst[n * Kd + k] = f2bf(src[e] * sc);
  }
}

// ---------------- pack x -> dense bf16 [G*257][256] ----------------
__global__ __launch_bounds__(256) void pack_xd_k(
    const float* __restrict__ x, const float* __restrict__ cls,
    const int* __restrict__ start, ushort* __restrict__ xd) {
  const size_t idx = (((size_t)blockIdx.x << 8) + threadIdx.x) << 3;  // 8 cols/thread
  const int row = (int)(idx >> 8);
  const int col = (int)(idx & 255);
  const int g = row / 257, n = row - g * 257;
  const int sg = start[g], cn = start[g + 1] - sg;
  float4 a, b;
  if (n < cn) {
    const float* src = x + (((size_t)(sg + n)) << 8) + col;
    a = ((const float4*)src)[0]; b = ((const float4*)src)[1];
  } else if (n == 256) {
    const float* src = cls + (((size_t)g) << 8) + col;
    a = ((const float4*)src)[0]; b = ((const float4*)src)[1];
  } else {
    a.x = a.y = a.z = a.w = 0.f; b = a;
  }
  ushort8 o;
  o[0] = f2bf(a.x); o[1] = f2bf(a.y); o[2] = f2bf(a.z); o[3] = f2bf(a.w);
  o[4] = f2bf(b.x); o[5] = f2bf(b.y); o[6] = f2bf(b.z); o[7] = f2bf(b.w);
  *(ushort8*)(xd + idx) = o;
}

// ============ GEMM variant A: 128x128 tile, 4 waves, 256 thr, single-buf 32KB, BK=64 ============
// EPI 0: +bias -> bf16 (by encodes (z, n-half) for fused QKV; Q bias scaled by QS2F)
// EPI 2: relu(+bias) -> bf16 (by = n-block of N)
// EPI 4: +bias + bf16 resid(dense m) -> bf16 SCATTERED to compact row r2
template<int EPI>
__device__ __forceinline__ void gemm_a_body(
    const ushort* __restrict__ A, const ushort* __restrict__ Bt,
    int N, int K,
    const float* __restrict__ b0, const float* __restrict__ b1, const float* __restrict__ b2,
    ushort* __restrict__ o0, ushort* __restrict__ o1, ushort* __restrict__ o2,
    const ushort* __restrict__ resid, const int* __restrict__ start) {
  __shared__ __align__(16) char As[16384];  // 128 x 128B, XOR-swizzled
  __shared__ __align__(16) char Bs[16384];
  const int tid = threadIdx.x, lane = tid & 63, wid = tid >> 6;
  const int hi = lane >> 4, lc = lane & 15;
  const int wm = wid >> 1, wn = wid & 1;

  const uint nx = gridDim.x, ny = gridDim.y;
  const uint hwid = blockIdx.y * nx + blockIdx.x;
  const uint wg = xcd_swz(hwid, nx * ny);
  const int bx = wg / ny, by = wg % ny;

  const int m0 = bx * 128;
  const int z = (EPI == 0) ? (by >> 1) : 0;
  const int ncol0 = (EPI == 0) ? (by & 1) * 128 : by * 128;
  const ushort* Bz = (EPI == 0) ? Bt + (size_t)z * 65536 : Bt;
  const float* bias = (EPI == 0) ? (z == 0 ? b0 : (z == 1 ? b1 : b2)) : b0;
  const float bmul = (EPI == 0 && z == 0) ? QS2F : 1.0f;
  ushort* obf = (EPI == 0) ? (z == 0 ? o0 : (z == 1 ? o1 : o2)) : o0;

  f32x4 acc[4][4];
#pragma unroll
  for (int a = 0; a < 4; ++a)
#pragma unroll
    for (int b = 0; b < 4; ++b) acc[a][b] = (f32x4)0.0f;

  for (int kt = 0; kt < K; kt += 64) {
#pragma unroll
    for (int r = 0; r < 4; ++r) {
      const int L = (r * 256 + tid) * 16;
      const int row = L >> 7;
      const int cb = (L & 127) ^ ((row & 7) << 4);
      gload16(A + (size_t)(m0 + row) * K + kt + (cb >> 1), As + L);
    }
#pragma unroll
    for (int r = 0; r < 4; ++r) {
      const int L = (r * 256 + tid) * 16;
      const int row = L >> 7;
      const int cb = (L & 127) ^ ((row & 7) << 4);
      gload16(Bz + (size_t)(ncol0 + row) * K + kt + (cb >> 1), Bs + L);
    }
    asm volatile("s_waitcnt vmcnt(0)" ::: "memory");
    __syncthreads();
#pragma unroll
    for (int ks = 0; ks < 2; ++ks) {
      short8 af[4], bfr[4];
      const int cB = (ks * 32 + hi * 8) * 2;
#pragma unroll
      for (int t = 0; t < 4; ++t) {
        const int rA = wm * 64 + t * 16 + lc;
        af[t] = *(const short8*)(As + (rA << 7) + (cB ^ ((rA & 7) << 4)));
        const int rB = wn * 64 + t * 16 + lc;
        bfr[t] = *(const short8*)(Bs + (rB << 7) + (cB ^ ((rB & 7) << 4)));
      }
#pragma unroll
      for (int mt = 0; mt < 4; ++mt)
#pragma unroll
        for (int nt = 0; nt < 4; ++nt)
          acc[mt][nt] = __builtin_amdgcn_mfma_f32_16x16x32_bf16(af[mt], bfr[nt], acc[mt][nt], 0, 0, 0);
    }
    __syncthreads();
  }

#pragma unroll
  for (int mt = 0; mt < 4; ++mt)
#pragma unroll
    for (int i = 0; i < 4; ++i) {
      const int m = m0 + wm * 64 + mt * 16 + hi * 4 + i;
      size_t r2 = (size_t)m;
      bool wr = true;
      if constexpr (EPI == 4) {
        // dense row m -> compact row r2 (nodes in x-order, then CLS block)
        const int gg = m / 257, nr = m - gg * 257;
        const int sg = start[gg], cn = start[gg + 1] - sg;
        if (nr < cn) r2 = (size_t)(sg + nr);
        else if (nr == 256) r2 = (size_t)(65536 + gg);
        else wr = false;
      }
#pragma unroll
      for (int nt = 0; nt < 4; ++nt) {
        const int n = ncol0 + wn * 64 + nt * 16 + lc;
        if constexpr (EPI == 0) {
          obf[(size_t)m * N + n] = f2bf(acc[mt][nt][i] + bias[n] * bmul);
        } else if constexpr (EPI == 2) {
          obf[(size_t)m * N + n] = f2bf(fmaxf(acc[mt][nt][i] + bias[n], 0.0f));
        } else if constexpr (EPI == 4) {
          if (wr) {
            const float v = acc[mt][nt][i] + bias[n] + bf2f(resid[((size_t)m << 8) + n]);
            obf[(r2 << 8) + n] = f2bf(v);
          }
        }
      }
    }
}

__global__ __launch_bounds__(256) void gemm_qkv(
    const ushort* A, const ushort* Bt, const float* bq, const float* bk, const float* bv,
    ushort* Q, ushort* K, ushort* V) {
  gemm_a_body<0>(A, Bt, 256, 256, bq, bk, bv, Q, K, V, nullptr, nullptr);
}
__global__ __launch_bounds__(256) void gemm_ffn1(
    const ushort* A, const ushort* Bt, const float* b1, ushort* t16) {
  gemm_a_body<2>(A, Bt, 512, 256, b1, nullptr, nullptr, t16, nullptr, nullptr,
                 nullptr, nullptr);
}
__global__ __launch_bounds__(256) void gemm_wo(
    const ushort* A, const ushort* Bt, const float* bo,
    ushort* hpre16, const ushort* resid, const int* start) {
  gemm_a_body<4>(A, Bt, 256, 256, bo, nullptr, nullptr, hpre16, nullptr, nullptr,
                 resid, start);
}

// ============ GEMM variant B128: 128x128 tile, 4 waves, 256 thr, single-buf 64KB, BK=128 ==
// Same structure as variant A but 128-wide K-slabs: HALF the stage->vmcnt(0)->barrier
// drains for K=512 (4 instead of 8). 256B LDS rows, same XOR swizzle (2-way banks).
// EPI 5: +bias + bf16 resid -> fp32;  EPI 6: +bias + bf16 resid -> bf16
template<int EPI>
__device__ __forceinline__ void gemm_b128_body(
    const ushort* __restrict__ A, const ushort* __restrict__ Bt, int K,
    const float* __restrict__ bias,
    ushort* __restrict__ o16, float* __restrict__ of32,
    const ushort* __restrict__ resid) {
  __shared__ __align__(16) char As[32768];  // 128 x 256B, XOR-swizzled
  __shared__ __align__(16) char Bs[32768];
  const int tid = threadIdx.x, lane = tid & 63, wid = tid >> 6;
  const int hi = lane >> 4, lc = lane & 15;
  const int wm = wid >> 1, wn = wid & 1;

  const uint nx = gridDim.x, ny = gridDim.y;
  const uint hwid = blockIdx.y * nx + blockIdx.x;
  const uint wg = xcd_swz(hwid, nx * ny);
  const int bx = wg / ny, by = wg % ny;
  const int m0 = bx * 128, ncol0 = by * 128;

  f32x4 acc[4][4];
#pragma unroll
  for (int a = 0; a < 4; ++a)
#pragma unroll
    for (int b = 0; b < 4; ++b) acc[a][b] = (f32x4)0.0f;

  for (int kt = 0; kt < K; kt += 128) {
#pragma unroll
    for (int r = 0; r < 8; ++r) {
      const int L = (r * 256 + tid) * 16;
      const int row = L >> 8;
      const int cb = (L & 255) ^ ((row & 7) << 4);
      gload16(A + (size_t)(m0 + row) * K + kt + (cb >> 1), As + L);
    }
#pragma unroll
    for (int r = 0; r < 8; ++r) {
      const int L = (r * 256 + tid) * 16;
      const int row = L >> 8;
      const int cb = (L & 255) ^ ((row & 7) << 4);
      gload16(Bt + (size_t)(ncol0 + row) * K + kt + (cb >> 1), Bs + L);
    }
    asm volatile("s_waitcnt vmcnt(0)" ::: "memory");
    __syncthreads();
#pragma unroll
    for (int ks = 0; ks < 4; ++ks) {
      short8 af[4], bfr[4];
      const int cB = (ks * 32 + hi * 8) * 2;
#pragma unroll
      for (int t = 0; t < 4; ++t) {
        const int rA = wm * 64 + t * 16 + lc;
        af[t] = *(const short8*)(As + (rA << 8) + (cB ^ ((rA & 7) << 4)));
        const int rB = wn * 64 + t * 16 + lc;
        bfr[t] = *(const short8*)(Bs + (rB << 8) + (cB ^ ((rB & 7) << 4)));
      }
#pragma unroll
      for (int mt = 0; mt < 4; ++mt)
#pragma unroll
        for (int nt = 0; nt < 4; ++nt)
          acc[mt][nt] = __builtin_amdgcn_mfma_f32_16x16x32_bf16(af[mt], bfr[nt], acc[mt][nt], 0, 0, 0);
    }
    __syncthreads();
  }

#pragma unroll
  for (int mt = 0; mt < 4; ++mt)
#pragma unroll
    for (int i = 0; i < 4; ++i) {
      const int m = m0 + wm * 64 + mt * 16 + hi * 4 + i;
#pragma unroll
      for (int nt = 0; nt < 4; ++nt) {
        const int n = ncol0 + wn * 64 + nt * 16 + lc;
        const float v = acc[mt][nt][i] + bias[n] + bf2f(resid[((size_t)m << 8) + n]);
        if constexpr (EPI == 6) o16[((size_t)m << 8) + n] = f2bf(v);
        else of32[((size_t)m << 8) + n] = v;
      }
    }
}

__global__ __launch_bounds__(256) void gemm_ffn2(
    const ushort* A, const ushort* Bt, const float* b2,
    float* out, const ushort* resid) {
  gemm_b128_body<5>(A, Bt, 512, b2, nullptr, out, resid);
}
__global__ __launch_bounds__(256) void gemm_ffn2b(
    const ushort* A, const ushort* Bt, const float* b2,
    ushort* fh16, const ushort* resid) {
  gemm_b128_body<6>(A, Bt, 512, b2, fh16, nullptr, resid);
}

// ---------------- streaming row-LayerNorm (256 cols), 8 rows/block ----------------
template<int IN_BF, int OUT_BF>
__global__ __launch_bounds__(512) void ln_k(const void* __restrict__ in,
                                            const float* __restrict__ gamma,
                                            const float* __restrict__ beta,
                                            void* __restrict__ outp) {
  const int lane = threadIdx.x & 63, wid = threadIdx.x >> 6;
  const size_t r = (size_t)blockIdx.x * 8 + wid;
  float f[4];
  if constexpr (IN_BF) {
    const ushort4v v = *(const ushort4v*)((const ushort*)in + (r << 8) + lane * 4);
    f[0] = bf2f(v[0]); f[1] = bf2f(v[1]); f[2] = bf2f(v[2]); f[3] = bf2f(v[3]);
  } else {
    const float4 v = *(const float4*)((const float*)in + (r << 8) + lane * 4);
    f[0] = v.x; f[1] = v.y; f[2] = v.z; f[3] = v.w;
  }
  float s = (f[0] + f[1]) + (f[2] + f[3]);
  float ss = (f[0] * f[0] + f[1] * f[1]) + (f[2] * f[2] + f[3] * f[3]);
#pragma unroll
  for (int m = 1; m < 64; m <<= 1) {
    s += __shfl_xor(s, m); ss += __shfl_xor(ss, m);
  }
  const float mu = s * (1.0f / 256.0f);
  const float rs = rsqrtf(ss * (1.0f / 256.0f) - mu * mu + 1e-5f);
  const float4 gv = *(const float4*)(gamma + lane * 4);
  const float4 bv = *(const float4*)(beta + lane * 4);
  float o[4];
  o[0] = (f[0] - mu) * rs * gv.x + bv.x;
  o[1] = (f[1] - mu) * rs * gv.y + bv.y;
  o[2] = (f[2] - mu) * rs * gv.z + bv.z;
  o[3] = (f[3] - mu) * rs * gv.w + bv.w;
  if constexpr (OUT_BF) {
    ushort4v u;
    u[0] = f2bf(o[0]); u[1] = f2bf(o[1]); u[2] = f2bf(o[2]); u[3] = f2bf(o[3]);
    *(ushort4v*)((ushort*)outp + (r << 8) + lane * 4) = u;
  } else {
    float4 u; u.x = o[0]; u.y = o[1]; u.z = o[2]; u.w = o[3];
    *(float4*)((float*)outp + (r << 8) + lane * 4) = u;
  }
}

// ---------------- attention: one block per (g, head); O may alias Kb ----------------
// 8 waves. Masking baked into K/V staging; Q pre-scaled by log2e -> RAW v_exp_f32.
// qt-PAIR per wave iteration: one K/V fragment read feeds two MFMAs (halves
// ds_read traffic, 2 independent dep-chains). P via LDS, 5 windows of 64 cols.
#define KSTR 40
#define VSTR 296
#define PSTR 72    // 64-col window + pad; 144B rows, word-stride 20 mod 32
#define OSTR 40
__global__ __launch_bounds__(512) void attn_k(
    const ushort* __restrict__ Q, const ushort* Kb,
    const ushort* __restrict__ Vb, const int* __restrict__ start,
    ushort* O) {
  __shared__ __align__(16) ushort Ks[272 * KSTR];     // 21760 B
  __shared__ __align__(16) ushort Vt[32 * VSTR];      // 18944 B
  __shared__ __align__(16) ushort Pb[8][32 * PSTR];   // 36864 B (2 windows/wave; Ot overlays)
  const int tid = threadIdx.x, lane = tid & 63, wid = tid >> 6;
  const int hi = lane >> 4, lo = lane & 15;
  const uint wg = xcd_swz(blockIdx.x, 2048);   // h-siblings -> same XCD (share K/V lines)
  const int g = wg >> 3, h = wg & 7;
  const int cnt = start[g + 1] - start[g];
  const size_t base = ((size_t)g * 257) * 256 + h * 32;

  for (int n = tid; n < 272; n += 512) {
    const bool rv = (n < cnt) || (n == 256);
    if (n < 257 && rv) {
      const ushort* src = Kb + base + ((size_t)n << 8);
#pragma unroll
      for (int j = 0; j < 4; ++j)
        *(ushort8*)(Ks + n * KSTR + j * 8) = *(const ushort8*)(src + j * 8);
    } else {
      const ushort8 zz = (ushort8)0;
#pragma unroll
      for (int j = 0; j < 4; ++j) *(ushort8*)(Ks + n * KSTR + j * 8) = zz;
    }
  }
  // V^T staging: packed b32 writes, consecutive lanes -> consecutive n words
  for (int u = tid; u < 576; u += 512) {
    const int npair = u % 144;
    const int d0 = (u / 144) * 8;
    const int n0 = npair * 2;
    const bool rv0 = (n0 < cnt) || (n0 == 256);
    const bool rv1 = (n0 + 1 < cnt) || (n0 + 1 == 256);
    ushort8 a8 = (ushort8)0, b8 = (ushort8)0;
    if (n0 < 257 && rv0) a8 = *(const ushort8*)(Vb + base + ((size_t)n0 << 8) + d0);
    if (n0 + 1 < 257 && rv1) b8 = *(const ushort8*)(Vb + base + ((size_t)(n0 + 1) << 8) + d0);
#pragma unroll
    for (int j = 0; j < 8; ++j)
      *(uint*)(Vt + (d0 + j) * VSTR + n0) = (uint)a8[j] | ((uint)b8[j] << 16);
  }
  __syncthreads();

  for (int qp = wid; qp < 9; qp += 8) {
    const int qt0 = qp * 2, qt1 = qp * 2 + 1;   // qt1 may be 17 (dummy)
    const int qr0 = qt0 * 16 + lo, qr1 = qt1 * 16 + lo;
    const int qc0 = qr0 < 257 ? qr0 : 256;
    const int qc1 = qr1 < 257 ? qr1 : 256;
    const short8 qf0 = *(const short8*)(Q + base + ((size_t)qc0 << 8) + hi * 8);
    const short8 qf1 = *(const short8*)(Q + base + ((size_t)qc1 << 8) + hi * 8);
    ushort* Pw0 = Pb[wid];
    ushort* Pw1 = Pb[wid] + 16 * PSTR;

    float den0 = -(float)(271 - cnt);   // dead cols contribute exp2(0)=1 each
    float den1 = den0;
    f32x4 o00 = (f32x4)0.0f, o01 = (f32x4)0.0f;
    f32x4 o10 = (f32x4)0.0f, o11 = (f32x4)0.0f;

#pragma unroll
    for (int ph = 0; ph < 5; ++ph) {
      const int ktB = ph * 4;
      const int ktE = (ph * 4 + 4 < 17) ? ph * 4 + 4 : 17;
      const int nb = ph * 64;
      float dl0 = 0.f, dl1 = 0.f;
      // QK^T pair + raw exp2 + pack -> P windows
#pragma unroll
      for (int kt = ktB; kt < ktE; ++kt) {
        const short8 kf = *(const short8*)(Ks + (kt * 16 + lo) * KSTR + hi * 8);
        const f32x4 s0 = __builtin_amdgcn_mfma_f32_16x16x32_bf16(kf, qf0, (f32x4)0.0f, 0, 0, 0);
        const f32x4 s1 = __builtin_amdgcn_mfma_f32_16x16x32_bf16(kf, qf1, (f32x4)0.0f, 0, 0, 0);
        const float a0 = ex2(s0[0]), a1 = ex2(s0[1]), a2 = ex2(s0[2]), a3 = ex2(s0[3]);
        dl0 += (a0 + a1) + (a2 + a3);
        uint2v w0; w0[0] = cvtpk(a0, a1); w0[1] = cvtpk(a2, a3);
        *(uint2v*)(Pw0 + lo * PSTR + (kt * 16 + hi * 4 - nb)) = w0;
        const float b0 = ex2(s1[0]), b1 = ex2(s1[1]), b2 = ex2(s1[2]), b3 = ex2(s1[3]);
        dl1 += (b0 + b1) + (b2 + b3);
        uint2v w1; w1[0] = cvtpk(b0, b1); w1[1] = cvtpk(b2, b3);
        *(uint2v*)(Pw1 + lo * PSTR + (kt * 16 + hi * 4 - nb)) = w1;
      }
      den0 += dl0; den1 += dl1;
      if (ph == 4) {  // zero-pad n=272..287 (window-rel 16..31)
        uint2v z0; z0[0] = 0u; z0[1] = 0u;
        *(uint2v*)(Pw0 + lo * PSTR + (16 + hi * 4)) = z0;
        *(uint2v*)(Pw1 + lo * PSTR + (16 + hi * 4)) = z0;
      }
      asm volatile("s_waitcnt lgkmcnt(0)" ::: "memory");
      __builtin_amdgcn_sched_barrier(0);
      // PV over this window: one V-frag read feeds both q-tiles
      __builtin_amdgcn_s_setprio(1);
      const int ksB = ph * 2;
      const int ksE = (ph * 2 + 2 < 9) ? ph * 2 + 2 : 9;
#pragma unroll
      for (int ks = ksB; ks < ksE; ++ks) {
        const short8 va0 = *(const short8*)(Vt + lo * VSTR + ks * 32 + hi * 8);
        const short8 va1 = *(const short8*)(Vt + (16 + lo) * VSTR + ks * 32 + hi * 8);
        const short8 p0 = *(const short8*)(Pw0 + lo * PSTR + (ks * 32 + hi * 8 - nb));
        const short8 p1 = *(const short8*)(Pw1 + lo * PSTR + (ks * 32 + hi * 8 - nb));
        o00 = __builtin_amdgcn_mfma_f32_16x16x32_bf16(va0, p0, o00, 0, 0, 0);
        o01 = __builtin_amdgcn_mfma_f32_16x16x32_bf16(va1, p0, o01, 0, 0, 0);
        o10 = __builtin_amdgcn_mfma_f32_16x16x32_bf16(va0, p1, o10, 0, 0, 0);
        o11 = __builtin_amdgcn_mfma_f32_16x16x32_bf16(va1, p1, o11, 0, 0, 0);
      }
      __builtin_amdgcn_s_setprio(0);
      __builtin_amdgcn_sched_barrier(0);  // pin: next window's writes stay below these reads
    }

    den0 += __shfl_xor(den0, 16); den0 += __shfl_xor(den0, 32);
    den1 += __shfl_xor(den1, 16); den1 += __shfl_xor(den1, 32);
    const float inv0 = 1.0f / den0;
    const float inv1 = 1.0f / den1;

    // normalize, transpose via per-wave LDS overlays, store both q-tiles
    {
      const uint w0 = cvtpk(o00[0] * inv0, o00[1] * inv0);
      const uint w1 = cvtpk(o00[2] * inv0, o00[3] * inv0);
      const uint w2 = cvtpk(o01[0] * inv0, o01[1] * inv0);
      const uint w3 = cvtpk(o01[2] * inv0, o01[3] * inv0);
      ushort* ob = Pw0 + lo * OSTR + hi * 4;
      *(uint*)(ob + 0) = w0;
      *(uint*)(ob + 2) = w1;
      *(uint*)(ob + 16) = w2;
      *(uint*)(ob + 18) = w3;
      const uint x0 = cvtpk(o10[0] * inv1, o10[1] * inv1);
      const uint x1 = cvtpk(o10[2] * inv1, o10[3] * inv1);
      const uint x2 = cvtpk(o11[0] * inv1, o11[1] * inv1);
      const uint x3 = cvtpk(o11[2] * inv1, o11[3] * inv1);
      ushort* ob1 = Pw1 + lo * OSTR + hi * 4;
      *(uint*)(ob1 + 0) = x0;
      *(uint*)(ob1 + 2) = x1;
      *(uint*)(ob1 + 16) = x2;
      *(uint*)(ob1 + 18) = x3;
    }
    asm volatile("s_waitcnt lgkmcnt(0)" ::: "memory");
    __builtin_amdgcn_sched_barrier(0);
    {
      const int r = lane >> 2;
      const ushort8 ov0 = *(const ushort8*)(Pw0 + r * OSTR + (lane & 3) * 8);
      const int q20 = qt0 * 16 + r;
      if (q20 < 257)
        *(ushort8*)(O + base + ((size_t)q20 << 8) + (lane & 3) * 8) = ov0;
      const ushort8 ov1 = *(const ushort8*)(Pw1 + r * OSTR + (lane & 3) * 8);
      const int q21 = qt1 * 16 + r;
      if (q21 < 257)
        *(ushort8*)(O + base + ((size_t)q21 << 8) + (lane & 3) * 8) = ov1;
    }
    __builtin_amdgcn_sched_barrier(0);
  }
}

extern "C" void kernel_launch(void* const* d_in, const int* in_sizes, int n_in,
                              void* d_out, int out_size, void* d_ws, size_t ws_size,
                              hipStream_t stream) {
  (void)in_sizes; (void)n_in; (void)out_size;
  const float* x     = (const float*)d_in[0];
  const int*   batch = (const int*)d_in[1];
  const float* cls   = (const float*)d_in[2];
  const float* Wq    = (const float*)d_in[3];
  const float* bq    = (const float*)d_in[4];
  const float* Wk    = (const float*)d_in[5];
  const float* bk    = (const float*)d_in[6];
  const float* Wv    = (const float*)d_in[7];
  const float* bv    = (const float*)d_in[8];
  const float* Wo    = (const float*)d_in[9];
  const float* bo    = (const float*)d_in[10];
  const float* g0    = (const float*)d_in[11];
  const float* beta0 = (const float*)d_in[12];
  const float* W1    = (const float*)d_in[13];
  const float* b1    = (const float*)d_in[14];
  const float* W2    = (const float*)d_in[15];
  const float* b2    = (const float*)d_in[16];
  const float* g1    = (const float*)d_in[17];
  const float* beta1 = (const float*)d_in[18];

  // Workspace (base plan peak 102.1 MB; +33.7 MB fh16 if ws allows):
  //   S1 @0      : Q -> hpre16 (wo out, COMPACT rows) -> tmid (spans S1+S2)
  //   S2 @33.7MB : K -> attn O (dense) -> tmid (upper)
  //   S3 @67.4MB : V -> h16 (LN0 out, compact; ffn1 A AND ffn2 resid)
  //   S4 @101MB  : fh16 (ffn2 bf16 out) [only if ws_size >= 135.8MB]
  // d_out: xd (bf16 dense in; QKV A AND wo resid) -> final out
  char* ws = (char*)d_ws;
  int*    start = (int*)ws;
  ushort* Wt    = (ushort*)(ws + 4096);
  char*   sbase = ws + 1052672;
  ushort* Qb    = (ushort*)(sbase);
  ushort* Kb2   = (ushort*)(sbase + 33685504);
  ushort* Vb2   = (ushort*)(sbase + 67371008);
  ushort* fh16  = (ushort*)(sbase + 101056512);
  ushort* hpre16 = Qb;
  ushort* h16   = Vb2;
  ushort* tmid  = Qb;                       // 65792x512 bf16 spans S1+S2
  ushort* xd    = (ushort*)d_out;
  float*  out   = (float*)d_out;
  const bool big_ws = ws_size >= (size_t)135794688;

  seg_start_k<<<256, 256, 0, stream>>>(batch, start);
  prep_w_k<<<dim3(512, 6), 256, 0, stream>>>(Wq, Wk, Wv, Wo, W1, W2, Wt);
  pack_xd_k<<<8224, 256, 0, stream>>>(x, cls, start, xd);
  gemm_qkv<<<dim3(514, 6), 256, 0, stream>>>(xd, Wt, bq, bk, bv, Qb, Kb2, Vb2);
  attn_k<<<2048, 512, 0, stream>>>(Qb, Kb2, Vb2, start, Kb2);   // O over K slot
  gemm_wo<<<dim3(514, 2), 256, 0, stream>>>(Kb2, Wt + 196608, bo, hpre16, xd, start);
  ln_k<1, 1><<<8224, 512, 0, stream>>>(hpre16, g0, beta0, h16);
  gemm_ffn1<<<dim3(514, 4), 256, 0, stream>>>(h16, Wt + 262144, b1, tmid);
  if (big_ws) {
    gemm_ffn2b<<<dim3(514, 2), 256, 0, stream>>>(tmid, Wt + 393216, b2, fh16, h16);
    ln_k<1, 0><<<8224, 512, 0, stream>>>(fh16, g1, beta1, out);
  } else {
    gemm_ffn2<<<dim3(514, 2), 256, 0, stream>>>(tmid, Wt + 393216, b2, out, h16);
    ln_k<0, 0><<<8224, 512, 0, stream>>>(out, g1, beta1, out);
  }
}